// Round 11
// baseline (342.994 us; speedup 1.0000x reference)
//
#include <hip/hip_runtime.h>
#include <stdint.h>

typedef unsigned int u32;
typedef short v8s __attribute__((ext_vector_type(8)));
typedef float v4f __attribute__((ext_vector_type(4)));

#define B_ 256
#define NF_ 1000000
#define LN_A 5.545177444479562f

__device__ inline u32 f2bf1(float a) {
    u32 x = __float_as_uint(a);
    return (x + 0x7fffu + ((x >> 16) & 1u)) >> 16;
}
__device__ inline float bfval(float a) { return __uint_as_float(f2bf1(a) << 16); }
__device__ inline u32 packbf(float lo, float hi) { return f2bf1(lo) | (f2bf1(hi) << 16); }
__device__ inline v8s as_v8s(uint4 x) { union { uint4 a; v8s b; } u; u.a = x; return u.b; }
__device__ inline v4f mfma16(v8s a, v8s b, v4f c) {
    return __builtin_amdgcn_mfma_f32_16x16x32_bf16(a, b, c, 0, 0, 0);
}
__device__ inline void wave_lds_fence() {
    asm volatile("s_waitcnt lgkmcnt(0)" ::: "memory");
}

// truncation-split of 8 consecutive fp32 -> bf16 hi + lo frags (hi+lo exact)
__device__ inline void split8(const float* p, v8s& hi, v8s& lo) {
    u32 h[4], l[4];
    #pragma unroll
    for (int i = 0; i < 4; ++i) {
        float2 f = *(const float2*)(p + 2*i);
        u32 xa = __float_as_uint(f.x), xb = __float_as_uint(f.y);
        h[i] = __builtin_amdgcn_perm(xb, xa, 0x07060302u);
        float la = f.x - __uint_as_float(xa & 0xffff0000u);
        float lb = f.y - __uint_as_float(xb & 0xffff0000u);
        l[i] = __builtin_amdgcn_perm(__float_as_uint(lb), __float_as_uint(la), 0x07060302u);
    }
    hi = as_v8s(make_uint4(h[0], h[1], h[2], h[3]));
    lo = as_v8s(make_uint4(l[0], l[1], l[2], l[3]));
}

// d_out scratch layout (dword offsets)
#define OFF_W2T_H 8192
#define OFF_W2T_L 16384
#define OFF_DIFF_H 24576
#define OFF_DIFF_L 28672
#define OFF_WCOMP 32768
#define OFF_BCOMP 33344
#define OFF_VC    33408
#define OFF_CW    102400
#define OFF_CB1   103680
#define OFF_PART  131072      // [256][16][64][2]
#define OFF_VC1   655360      // [256][4][128]

// ---------------------------------------------------------------------------
// w_prep (verified r4-r10)
// ---------------------------------------------------------------------------
__global__ __launch_bounds__(256) void w_prep(
    const float* __restrict__ x,   const float* __restrict__ w1c,
    const float* __restrict__ b1c, const float* __restrict__ w2c,
    const float* __restrict__ b2c, const float* __restrict__ w2l,
    const float* __restrict__ diff, u32* __restrict__ scr)
{
    int idx = blockIdx.x * 256 + threadIdx.x;
    float* scf = (float*)scr;
    if (idx < 8192) {
        int j = idx >> 6, c = idx & 63;
        float v0 = w2l[j*128 + 2*c], v1 = w2l[j*128 + 2*c + 1];
        scr[OFF_W2T_H + idx] = packbf(v0, v1);
        scr[OFF_W2T_L + idx] = packbf(v0 - bfval(v0), v1 - bfval(v1));
    } else if (idx < 12288) {
        int r = idx - 8192, a = r >> 6, c = r & 63;
        float v0 = diff[a*128 + 2*c], v1 = diff[a*128 + 2*c + 1];
        scr[OFF_DIFF_H + r] = packbf(v0, v1);
        scr[OFF_DIFF_L + r] = packbf(v0 - bfval(v0), v1 - bfval(v1));
    } else if (idx < 12864) {
        int r = idx - 12288, j = r >> 6, o = r & 63;
        float s = 0.0f;
        for (int k1 = 0; k1 < 5; ++k1) {
            int k2 = j - k1;
            if (k2 < 0 || k2 > 4) continue;
            for (int i = 0; i < 32; ++i)
                s += w1c[i*5 + k1] * w2c[o*160 + i*5 + k2];
        }
        scf[OFF_WCOMP + r] = s;
    } else if (idx < 12928) {
        int o = idx - 12864;
        float s = b2c[o];
        for (int i = 0; i < 32; ++i) {
            float b1 = b1c[i];
            for (int k2 = 0; k2 < 5; ++k2) s += w2c[o*160 + i*5 + k2] * b1;
        }
        scf[OFF_BCOMP + o] = s;
    } else if (idx >= 13056 && idx < 78592) {
        int r = idx - 13056;
        int b = r >> 8, q = (r >> 6) & 3, o = r & 63;
        float x0 = x[b*2000], x1 = x[b*2000 + 1];
        float xa = x[b*2000 + 1998], xb = x[b*2000 + 1999];
        float s = 0.0f;
        for (int i = 0; i < 32; ++i) {
            float b1 = b1c[i];
            if (q == 0) {
                float hvm2 = b1 + w1c[i*5 + 4]*x0;
                float hvm1 = b1 + w1c[i*5 + 3]*x0 + w1c[i*5 + 4]*x1;
                s += w2c[o*160 + i*5 + 0]*hvm2 + w2c[o*160 + i*5 + 1]*hvm1;
            } else if (q == 1) {
                float hvm1 = b1 + w1c[i*5 + 3]*x0 + w1c[i*5 + 4]*x1;
                s += w2c[o*160 + i*5 + 0]*hvm1;
            } else if (q == 2) {
                float hv0 = b1 + w1c[i*5 + 0]*xa + w1c[i*5 + 1]*xb;
                s += w2c[o*160 + i*5 + 4]*hv0;
            } else {
                float hv0 = b1 + w1c[i*5 + 0]*xa + w1c[i*5 + 1]*xb;
                float hv1 = b1 + w1c[i*5 + 0]*xb;
                s += w2c[o*160 + i*5 + 3]*hv0 + w2c[o*160 + i*5 + 4]*hv1;
            }
        }
        scf[OFF_VC + r] = s;
    }
}

// ---------------------------------------------------------------------------
// k_prep2 v11: w1l staged in LDS (coalesced once) — kills the per-thread
// 256-B-line re-reads of the Vc1 loop.
// ---------------------------------------------------------------------------
__global__ __launch_bounds__(256) void k_prep2(
    const float* __restrict__ w1l, const float* __restrict__ b1l,
    u32* __restrict__ scr)
{
    __shared__ float w1s[8192];
    for (int i = threadIdx.x; i < 8192; i += 256) w1s[i] = w1l[i];
    __syncthreads();

    const float* scf = (const float*)scr;
    float* out = (float*)scr;
    int idx = blockIdx.x * 256 + threadIdx.x;
    if (idx < 1152) {
        int tap = idx >> 7, j = idx & 127;
        float s = 0.f;
        for (int o = 0; o < 64; ++o)
            s += w1s[j*64 + o] * scf[OFF_WCOMP + tap*64 + o];
        out[OFF_CW + idx] = s;
    } else if (idx < 1280) {
        int j = idx - 1152;
        float s = b1l[j];
        for (int o = 0; o < 64; ++o)
            s += w1s[j*64 + o] * scf[OFF_BCOMP + o];
        out[OFF_CB1 + j] = s;
    } else if (idx < 1280 + 131072) {
        int r = idx - 1280;
        int bq = r >> 7, j = r & 127;
        float s = 0.f;
        for (int o = 0; o < 64; ++o)
            s += w1s[j*64 + o] * scf[OFF_VC + bq*64 + o];
        out[OFF_VC1 + r] = s;
    }
}

// ---------------------------------------------------------------------------
// k_front v11: identical math to v10; U stores are NON-TEMPORAL so the
// 131 MB stream doesn't evict the weight/diff images from L2.
// ---------------------------------------------------------------------------
__global__ __launch_bounds__(256, 3) void k_front(
    const float* __restrict__ x,   const float* __restrict__ b2l,
    const float* __restrict__ CW,  const float* __restrict__ cb1,
    const float* __restrict__ Vc1,
    const uint4* __restrict__ w2h, const uint4* __restrict__ w2lo,
    const uint4* __restrict__ dh,  const uint4* __restrict__ dl,
    const float* __restrict__ baseline, const int* __restrict__ regions,
    float* __restrict__ U, float* __restrict__ partials)
{
    __shared__ float smf[9136];
    const int b     = blockIdx.x >> 4;
    const int chunk = blockIdx.x & 15;
    const int t     = threadIdx.x;
    const int lane  = t & 63;
    const int w     = __builtin_amdgcn_readfirstlane(t >> 6);
    const int n16   = lane & 15;
    const int q     = lane >> 4;
    const int l0w   = (chunk << 7) + w*32;
    const int rrow  = regions[b];

    float* Aw   = smf + w*2156;
    float* xsw  = Aw + 2112;
    float* sred = smf + 8624;
    u32*  estd  = (u32*)Aw;
    uint16_t* esth = (uint16_t*)Aw;

    if (lane < 44) {
        int g = l0w - 4 + lane;
        xsw[lane] = (g >= 0 && g < 2000) ? x[b*2000 + g] : 0.0f;
    }
    wave_lds_fence();

    float cw0[9], cw1[9];
    #pragma unroll
    for (int d = 0; d < 9; ++d) {
        float2 c2 = *(const float2*)&CW[d*128 + 2*lane];
        cw0[d] = c2.x; cw1[d] = c2.y;
    }
    const float2 cb2 = *(const float2*)&cb1[2*lane];

    v8s a2h[2][4], a2l[2][4];
    #pragma unroll
    for (int mt = 0; mt < 2; ++mt) {
        float win[9];
        #pragma unroll
        for (int d = 0; d < 9; ++d) win[d] = xsw[mt*16 + d];
        #pragma unroll
        for (int r = 0; r < 16; ++r) {
            int gl = l0w + mt*16 + r;
            float h0 = cb2.x, h1v = cb2.y;
            #pragma unroll
            for (int d = 0; d < 9; ++d) { h0 += win[d]*cw0[d]; h1v += win[d]*cw1[d]; }
            if (gl <= 1) {
                float2 v = *(const float2*)&Vc1[(b*4 + gl)*128 + 2*lane];
                h0 -= v.x; h1v -= v.y;
            } else if (gl >= 1998 && gl < 2000) {
                float2 v = *(const float2*)&Vc1[(b*4 + gl - 1996)*128 + 2*lane];
                h0 -= v.x; h1v -= v.y;
            }
            *(float2*)&Aw[r*130 + 2*lane] = make_float2(fmaxf(h0, 0.f), fmaxf(h1v, 0.f));
            #pragma unroll
            for (int d = 0; d < 8; ++d) win[d] = win[d+1];
            win[8] = xsw[mt*16 + r + 9];
        }
        wave_lds_fence();
        #pragma unroll
        for (int kc = 0; kc < 4; ++kc)
            split8(&Aw[n16*130 + kc*32 + q*8], a2h[mt][kc], a2l[mt][kc]);
        wave_lds_fence();
    }

    // lin2 + relu: M=32 N=128 K=128 (3-term split-bf16)
    v4f acc2[2][8];
    #pragma unroll
    for (int nt = 0; nt < 8; ++nt) {
        float bias = b2l[nt*16 + n16];
        acc2[0][nt] = (v4f){bias, bias, bias, bias};
        acc2[1][nt] = (v4f){bias, bias, bias, bias};
    }
    #pragma unroll
    for (int nt = 0; nt < 8; ++nt) {
        int j2 = nt*16 + n16;
        #pragma unroll
        for (int kc = 0; kc < 4; ++kc) {
            v8s bh = as_v8s(w2h [j2*16 + kc*4 + q]);
            v8s bl = as_v8s(w2lo[j2*16 + kc*4 + q]);
            acc2[0][nt] = mfma16(a2h[0][kc], bh, acc2[0][nt]);
            acc2[0][nt] = mfma16(a2l[0][kc], bh, acc2[0][nt]);
            acc2[0][nt] = mfma16(a2h[0][kc], bl, acc2[0][nt]);
            acc2[1][nt] = mfma16(a2h[1][kc], bh, acc2[1][nt]);
            acc2[1][nt] = mfma16(a2l[1][kc], bh, acc2[1][nt]);
            acc2[1][nt] = mfma16(a2h[1][kc], bl, acc2[1][nt]);
        }
    }

    // relu + RNE bf16 -> est
    #pragma unroll
    for (int mt = 0; mt < 2; ++mt)
        #pragma unroll
        for (int nt = 0; nt < 8; ++nt)
            #pragma unroll
            for (int rg = 0; rg < 4; ++rg) {
                float v = fmaxf(acc2[mt][nt][rg], 0.0f);
                int rr = mt*16 + q*4 + rg;
                esth[rr*132 + nt*16 + n16] = (uint16_t)f2bf1(v);
            }
    wave_lds_fence();

    // lse A-frags from est
    v8s af[2][4];
    #pragma unroll
    for (int mt = 0; mt < 2; ++mt)
        #pragma unroll
        for (int kc = 0; kc < 4; ++kc) {
            int ba = (mt*16 + n16)*66 + kc*16 + q*4;
            uint2 p0 = *(const uint2*)(estd + ba);
            uint2 p1 = *(const uint2*)(estd + ba + 2);
            af[mt][kc] = as_v8s(make_uint4(p0.x, p0.y, p1.x, p1.y));
        }
    wave_lds_fence();   // est fully read -> U overlay safe

    float blv[2][4];
    bool  vl[2][4];
    #pragma unroll
    for (int mt = 0; mt < 2; ++mt)
        #pragma unroll
        for (int rg = 0; rg < 4; ++rg) {
            int rl = l0w + mt*16 + q*4 + rg;
            vl[mt][rg] = rl < 2000;
            blv[mt][rg] = baseline[rrow*2000 + (rl < 2000 ? rl : 1999)];
        }

    #pragma unroll
    for (int nt = 0; nt < 4; ++nt) {
        v4f acc0 = (v4f){0.f,0.f,0.f,0.f}, acc1 = (v4f){0.f,0.f,0.f,0.f};
        #pragma unroll
        for (int kc = 0; kc < 4; ++kc) {
            v8s bh = as_v8s(dh[(nt*16 + n16)*16 + kc*4 + q]);
            v8s bl = as_v8s(dl[(nt*16 + n16)*16 + kc*4 + q]);
            acc0 = mfma16(af[0][kc], bh, acc0);
            acc1 = mfma16(af[1][kc], bh, acc1);
            acc0 = mfma16(af[0][kc], bl, acc0);
            acc1 = mfma16(af[1][kc], bl, acc1);
        }
        #pragma unroll
        for (int rg = 0; rg < 4; ++rg) {
            Aw[(q*4 + rg)*65      + nt*16 + n16] = acc0[rg] + blv[0][rg];
            Aw[(16 + q*4 + rg)*65 + nt*16 + n16] = acc1[rg] + blv[1][rg];
        }
        float m = -3.0e38f, s = 0.0f;
        #pragma unroll
        for (int rg = 0; rg < 4; ++rg) {
            float u = acc0[rg] + blv[0][rg];
            if (vl[0][rg]) {
                float mn = fmaxf(m, u);
                s = s * __expf(m - mn) + __expf(u - mn);
                m = mn;
            }
        }
        #pragma unroll
        for (int rg = 0; rg < 4; ++rg) {
            float u = acc1[rg] + blv[1][rg];
            if (vl[1][rg]) {
                float mn = fmaxf(m, u);
                s = s * __expf(m - mn) + __expf(u - mn);
                m = mn;
            }
        }
        #pragma unroll
        for (int off = 16; off < 64; off <<= 1) {
            float m2 = __shfl_xor(m, off, 64);
            float s2 = __shfl_xor(s, off, 64);
            float mn = fmaxf(m, m2);
            s = s * __expf(m - mn) + s2 * __expf(m2 - mn);
            m = mn;
        }
        if (q == 0) {
            sred[(w*64 + nt*16 + n16)*2 + 0] = m;
            sred[(w*64 + nt*16 + n16)*2 + 1] = s;
        }
    }
    wave_lds_fence();

    // coalesced NON-TEMPORAL U store (don't evict images from L2)
    #pragma unroll
    for (int c = 0; c < 8; ++c) {
        int row = c*4 + (lane >> 4);
        int col = (lane & 15) * 4;
        int glr = l0w + row;
        if (glr < 2000) {
            const float* src = Aw + row*65 + col;
            v4f v = {src[0], src[1], src[2], src[3]};
            __builtin_nontemporal_store(v, (v4f*)(U + ((size_t)(b*2000 + glr))*64 + col));
        }
    }

    __syncthreads();   // sred visible block-wide
    if (t < 64) {
        float m = sred[t*2 + 0], s = sred[t*2 + 1];
        #pragma unroll
        for (int ww = 1; ww < 4; ++ww) {
            float m2 = sred[(ww*64 + t)*2 + 0], s2 = sred[(ww*64 + t)*2 + 1];
            float mn = fmaxf(m, m2);
            s = s * __expf(m - mn) + s2 * __expf(m2 - mn);
            m = mn;
        }
        partials[((b*16 + chunk)*64 + t)*2 + 0] = m;
        partials[((b*16 + chunk)*64 + t)*2 + 1] = s;
    }
}

__global__ __launch_bounds__(64) void k_red(
    const float* __restrict__ partials, float* __restrict__ lse)
{
    int b = blockIdx.x, a = threadIdx.x;
    float m = -3.0e38f, s = 0.0f;
    for (int c = 0; c < 16; ++c) {
        float pm = partials[((b*16 + c)*64 + a)*2 + 0];
        float ps = partials[((b*16 + c)*64 + a)*2 + 1];
        float mn = fmaxf(m, pm);
        s = s * __expf(m - mn) + ps * __expf(pm - mn);
        m = mn;
    }
    lse[b*64 + a] = m + __logf(s);
}

// ---------------------------------------------------------------------------
// k_gather2 v11: 4 fragments/thread, batched index loads then 4 independent
// U point-load chains.
// ---------------------------------------------------------------------------
#define GR2 4
__global__ __launch_bounds__(256) void k_gather2(
    const float* __restrict__ U, const float* __restrict__ lse,
    const int* __restrict__ labels, const int* __restrict__ cellix,
    const int* __restrict__ regionix, const int* __restrict__ binix,
    float* __restrict__ out)
{
    const int base = blockIdx.x * (256*GR2) + threadIdx.x;
    int f[GR2], bb[GR2], ll[GR2], aa[GR2];
    bool val[GR2];
    #pragma unroll
    for (int p = 0; p < GR2; ++p) {
        f[p] = base + p*256;
        val[p] = f[p] < NF_;
        int fc = val[p] ? f[p] : 0;
        bb[p] = regionix[fc];
        ll[p] = binix[fc];
        aa[p] = cellix[fc];
    }
    #pragma unroll
    for (int p = 0; p < GR2; ++p) aa[p] = labels[aa[p]];

    float uv[GR2], ls[GR2];
    #pragma unroll
    for (int p = 0; p < GR2; ++p)
        uv[p] = U[((size_t)(bb[p]*2000 + ll[p]))*64 + aa[p]];
    #pragma unroll
    for (int p = 0; p < GR2; ++p)
        ls[p] = lse[bb[p]*64 + aa[p]];
    #pragma unroll
    for (int p = 0; p < GR2; ++p)
        if (val[p]) out[f[p]] = uv[p] - ls[p] + LN_A;
}

extern "C" void kernel_launch(void* const* d_in, const int* in_sizes, int n_in,
                              void* d_out, int out_size, void* d_ws, size_t ws_size,
                              hipStream_t stream)
{
    const float* bincounts = (const float*)d_in[0];
    const float* conv1_w   = (const float*)d_in[1];
    const float* conv1_b   = (const float*)d_in[2];
    const float* conv2_w   = (const float*)d_in[3];
    const float* conv2_b   = (const float*)d_in[4];
    const float* lin1_w    = (const float*)d_in[5];
    const float* lin1_b    = (const float*)d_in[6];
    const float* lin2_w    = (const float*)d_in[7];
    const float* lin2_b    = (const float*)d_in[8];
    const float* baseline  = (const float*)d_in[9];
    const float* diff      = (const float*)d_in[10];
    const int*   regions   = (const int*)d_in[11];
    const int*   labels    = (const int*)d_in[12];
    const int*   cellix    = (const int*)d_in[13];
    const int*   regionix  = (const int*)d_in[14];
    const int*   binix     = (const int*)d_in[15];
    float* out = (float*)d_out;
    u32*   scr = (u32*)d_out;    // d_out doubles as scratch until k_gather2

    // ws: U fp32 [256*2000][64] = 131,072,000 B | lse f32 [256*64]
    const size_t u_words = (size_t)B_ * 2000 * 64;
    const size_t need = u_words*4 + (size_t)B_*64*4;
    if (ws_size < need) return;
    float* U   = (float*)d_ws;
    float* lse = U + u_words;

    const float* scf = (const float*)scr;
    float* partials = (float*)(scr + OFF_PART);

    w_prep  <<<dim3(307), dim3(256), 0, stream>>>(bincounts, conv1_w, conv1_b, conv2_w,
                                                  conv2_b, lin2_w, diff, scr);
    k_prep2 <<<dim3(518), dim3(256), 0, stream>>>(lin1_w, lin1_b, scr);
    k_front <<<dim3(B_*16), dim3(256), 0, stream>>>(bincounts, lin2_b,
                                                    scf + OFF_CW, scf + OFF_CB1,
                                                    scf + OFF_VC1,
                                                    (const uint4*)(scr + OFF_W2T_H),
                                                    (const uint4*)(scr + OFF_W2T_L),
                                                    (const uint4*)(scr + OFF_DIFF_H),
                                                    (const uint4*)(scr + OFF_DIFF_L),
                                                    baseline, regions, U, partials);
    k_red   <<<dim3(B_), dim3(64), 0, stream>>>(partials, lse);
    k_gather2<<<dim3((NF_ + 256*GR2 - 1) / (256*GR2)), dim3(256), 0, stream>>>(
        U, lse, labels, cellix, regionix, binix, out);
}

// Round 12
// 253.864 us; speedup vs baseline: 1.3511x; 1.3511x over previous
//
#include <hip/hip_runtime.h>
#include <stdint.h>

typedef unsigned int u32;
typedef short v8s __attribute__((ext_vector_type(8)));
typedef float v4f __attribute__((ext_vector_type(4)));

#define B_ 256
#define NF_ 1000000
#define LN_A 5.545177444479562f

__device__ inline u32 f2bf1(float a) {
    u32 x = __float_as_uint(a);
    return (x + 0x7fffu + ((x >> 16) & 1u)) >> 16;
}
__device__ inline float bfval(float a) { return __uint_as_float(f2bf1(a) << 16); }
__device__ inline u32 packbf(float lo, float hi) { return f2bf1(lo) | (f2bf1(hi) << 16); }
__device__ inline v8s as_v8s(uint4 x) { union { uint4 a; v8s b; } u; u.a = x; return u.b; }
__device__ inline v4f mfma16(v8s a, v8s b, v4f c) {
    return __builtin_amdgcn_mfma_f32_16x16x32_bf16(a, b, c, 0, 0, 0);
}
__device__ inline void wave_lds_fence() {
    asm volatile("s_waitcnt lgkmcnt(0)" ::: "memory");
}

// truncation-split of 8 consecutive fp32 -> bf16 hi + lo frags (hi+lo exact)
__device__ inline void split8(const float* p, v8s& hi, v8s& lo) {
    u32 h[4], l[4];
    #pragma unroll
    for (int i = 0; i < 4; ++i) {
        float2 f = *(const float2*)(p + 2*i);
        u32 xa = __float_as_uint(f.x), xb = __float_as_uint(f.y);
        h[i] = __builtin_amdgcn_perm(xb, xa, 0x07060302u);
        float la = f.x - __uint_as_float(xa & 0xffff0000u);
        float lb = f.y - __uint_as_float(xb & 0xffff0000u);
        l[i] = __builtin_amdgcn_perm(__float_as_uint(lb), __float_as_uint(la), 0x07060302u);
    }
    hi = as_v8s(make_uint4(h[0], h[1], h[2], h[3]));
    lo = as_v8s(make_uint4(l[0], l[1], l[2], l[3]));
}

// d_out scratch layout (dword offsets)
#define OFF_W2T_H 8192
#define OFF_W2T_L 16384
#define OFF_DIFF_H 24576
#define OFF_DIFF_L 28672
#define OFF_WCOMP 32768
#define OFF_BCOMP 33344
#define OFF_VC    33408
#define OFF_CW    102400
#define OFF_CB1   103680
#define OFF_PART  131072      // [256][16][64][2]
#define OFF_VC1   655360      // [256][4][128]

// ---------------------------------------------------------------------------
// w_prep v12: images now FRAG-MAJOR — uint4 index (nt*4+kc)*64 + lane, so a
// wave's frag load is one contiguous 1-KB segment (was 16 x 64-B segments).
// Values identical to r4-r11 (index permutation only).
// ---------------------------------------------------------------------------
__global__ __launch_bounds__(256) void w_prep(
    const float* __restrict__ x,   const float* __restrict__ w1c,
    const float* __restrict__ b1c, const float* __restrict__ w2c,
    const float* __restrict__ b2c, const float* __restrict__ w2l,
    const float* __restrict__ diff, u32* __restrict__ scr)
{
    int idx = blockIdx.x * 256 + threadIdx.x;
    float* scf = (float*)scr;
    if (idx < 8192) {                        // w2 frag-major (nt 0..7)
        int inew = idx >> 2, comp = idx & 3;
        int nt = inew >> 8, kc = (inew >> 6) & 3, lane = inew & 63;
        int j = nt*16 + (lane & 15);
        int c = kc*16 + (lane >> 4)*4 + comp;
        float v0 = w2l[j*128 + 2*c], v1 = w2l[j*128 + 2*c + 1];
        scr[OFF_W2T_H + idx] = packbf(v0, v1);
        scr[OFF_W2T_L + idx] = packbf(v0 - bfval(v0), v1 - bfval(v1));
    } else if (idx < 12288) {                // diff frag-major (nt 0..3)
        int r = idx - 8192;
        int inew = r >> 2, comp = r & 3;
        int nt = inew >> 8, kc = (inew >> 6) & 3, lane = inew & 63;
        int a = nt*16 + (lane & 15);
        int c = kc*16 + (lane >> 4)*4 + comp;
        float v0 = diff[a*128 + 2*c], v1 = diff[a*128 + 2*c + 1];
        scr[OFF_DIFF_H + r] = packbf(v0, v1);
        scr[OFF_DIFF_L + r] = packbf(v0 - bfval(v0), v1 - bfval(v1));
    } else if (idx < 12864) {
        int r = idx - 12288, j = r >> 6, o = r & 63;
        float s = 0.0f;
        for (int k1 = 0; k1 < 5; ++k1) {
            int k2 = j - k1;
            if (k2 < 0 || k2 > 4) continue;
            for (int i = 0; i < 32; ++i)
                s += w1c[i*5 + k1] * w2c[o*160 + i*5 + k2];
        }
        scf[OFF_WCOMP + r] = s;
    } else if (idx < 12928) {
        int o = idx - 12864;
        float s = b2c[o];
        for (int i = 0; i < 32; ++i) {
            float b1 = b1c[i];
            for (int k2 = 0; k2 < 5; ++k2) s += w2c[o*160 + i*5 + k2] * b1;
        }
        scf[OFF_BCOMP + o] = s;
    } else if (idx >= 13056 && idx < 78592) {
        int r = idx - 13056;
        int b = r >> 8, q = (r >> 6) & 3, o = r & 63;
        float x0 = x[b*2000], x1 = x[b*2000 + 1];
        float xa = x[b*2000 + 1998], xb = x[b*2000 + 1999];
        float s = 0.0f;
        for (int i = 0; i < 32; ++i) {
            float b1 = b1c[i];
            if (q == 0) {
                float hvm2 = b1 + w1c[i*5 + 4]*x0;
                float hvm1 = b1 + w1c[i*5 + 3]*x0 + w1c[i*5 + 4]*x1;
                s += w2c[o*160 + i*5 + 0]*hvm2 + w2c[o*160 + i*5 + 1]*hvm1;
            } else if (q == 1) {
                float hvm1 = b1 + w1c[i*5 + 3]*x0 + w1c[i*5 + 4]*x1;
                s += w2c[o*160 + i*5 + 0]*hvm1;
            } else if (q == 2) {
                float hv0 = b1 + w1c[i*5 + 0]*xa + w1c[i*5 + 1]*xb;
                s += w2c[o*160 + i*5 + 4]*hv0;
            } else {
                float hv0 = b1 + w1c[i*5 + 0]*xa + w1c[i*5 + 1]*xb;
                float hv1 = b1 + w1c[i*5 + 0]*xb;
                s += w2c[o*160 + i*5 + 3]*hv0 + w2c[o*160 + i*5 + 4]*hv1;
            }
        }
        scf[OFF_VC + r] = s;
    }
}

// ---------------------------------------------------------------------------
// k_prep2 (verified r11): w1l staged in LDS
// ---------------------------------------------------------------------------
__global__ __launch_bounds__(256) void k_prep2(
    const float* __restrict__ w1l, const float* __restrict__ b1l,
    u32* __restrict__ scr)
{
    __shared__ float w1s[8192];
    for (int i = threadIdx.x; i < 8192; i += 256) w1s[i] = w1l[i];
    __syncthreads();

    const float* scf = (const float*)scr;
    float* out = (float*)scr;
    int idx = blockIdx.x * 256 + threadIdx.x;
    if (idx < 1152) {
        int tap = idx >> 7, j = idx & 127;
        float s = 0.f;
        for (int o = 0; o < 64; ++o)
            s += w1s[j*64 + o] * scf[OFF_WCOMP + tap*64 + o];
        out[OFF_CW + idx] = s;
    } else if (idx < 1280) {
        int j = idx - 1152;
        float s = b1l[j];
        for (int o = 0; o < 64; ++o)
            s += w1s[j*64 + o] * scf[OFF_BCOMP + o];
        out[OFF_CB1 + j] = s;
    } else if (idx < 1280 + 131072) {
        int r = idx - 1280;
        int bq = r >> 7, j = r & 127;
        float s = 0.f;
        for (int o = 0; o < 64; ++o)
            s += w1s[j*64 + o] * scf[OFF_VC + bq*64 + o];
        out[OFF_VC1 + r] = s;
    }
}

// ---------------------------------------------------------------------------
// k_front v12: same math as v10/v11; frag-major image reads (1-KB coalesced),
// baseline loads hoisted ahead of the MFMA section, nt U stores.
// ---------------------------------------------------------------------------
__global__ __launch_bounds__(256, 3) void k_front(
    const float* __restrict__ x,   const float* __restrict__ b2l,
    const float* __restrict__ CW,  const float* __restrict__ cb1,
    const float* __restrict__ Vc1,
    const uint4* __restrict__ w2h, const uint4* __restrict__ w2lo,
    const uint4* __restrict__ dh,  const uint4* __restrict__ dl,
    const float* __restrict__ baseline, const int* __restrict__ regions,
    float* __restrict__ U, float* __restrict__ partials)
{
    __shared__ float smf[9136];
    const int b     = blockIdx.x >> 4;
    const int chunk = blockIdx.x & 15;
    const int t     = threadIdx.x;
    const int lane  = t & 63;
    const int w     = __builtin_amdgcn_readfirstlane(t >> 6);
    const int n16   = lane & 15;
    const int q     = lane >> 4;
    const int l0w   = (chunk << 7) + w*32;
    const int rrow  = regions[b];

    float* Aw   = smf + w*2156;
    float* xsw  = Aw + 2112;
    float* sred = smf + 8624;
    u32*  estd  = (u32*)Aw;
    uint16_t* esth = (uint16_t*)Aw;

    if (lane < 44) {
        int g = l0w - 4 + lane;
        xsw[lane] = (g >= 0 && g < 2000) ? x[b*2000 + g] : 0.0f;
    }
    wave_lds_fence();

    float cw0[9], cw1[9];
    #pragma unroll
    for (int d = 0; d < 9; ++d) {
        float2 c2 = *(const float2*)&CW[d*128 + 2*lane];
        cw0[d] = c2.x; cw1[d] = c2.y;
    }
    const float2 cb2 = *(const float2*)&cb1[2*lane];

    // hoisted baseline loads (independent of all compute below)
    float blv[2][4];
    bool  vl[2][4];
    #pragma unroll
    for (int mt = 0; mt < 2; ++mt)
        #pragma unroll
        for (int rg = 0; rg < 4; ++rg) {
            int rl = l0w + mt*16 + q*4 + rg;
            vl[mt][rg] = rl < 2000;
            blv[mt][rg] = baseline[rrow*2000 + (rl < 2000 ? rl : 1999)];
        }

    v8s a2h[2][4], a2l[2][4];
    #pragma unroll
    for (int mt = 0; mt < 2; ++mt) {
        float win[9];
        #pragma unroll
        for (int d = 0; d < 9; ++d) win[d] = xsw[mt*16 + d];
        #pragma unroll
        for (int r = 0; r < 16; ++r) {
            int gl = l0w + mt*16 + r;
            float h0 = cb2.x, h1v = cb2.y;
            #pragma unroll
            for (int d = 0; d < 9; ++d) { h0 += win[d]*cw0[d]; h1v += win[d]*cw1[d]; }
            if (gl <= 1) {
                float2 v = *(const float2*)&Vc1[(b*4 + gl)*128 + 2*lane];
                h0 -= v.x; h1v -= v.y;
            } else if (gl >= 1998 && gl < 2000) {
                float2 v = *(const float2*)&Vc1[(b*4 + gl - 1996)*128 + 2*lane];
                h0 -= v.x; h1v -= v.y;
            }
            *(float2*)&Aw[r*130 + 2*lane] = make_float2(fmaxf(h0, 0.f), fmaxf(h1v, 0.f));
            #pragma unroll
            for (int d = 0; d < 8; ++d) win[d] = win[d+1];
            win[8] = xsw[mt*16 + r + 9];
        }
        wave_lds_fence();
        #pragma unroll
        for (int kc = 0; kc < 4; ++kc)
            split8(&Aw[n16*130 + kc*32 + q*8], a2h[mt][kc], a2l[mt][kc]);
        wave_lds_fence();
    }

    // lin2 + relu: M=32 N=128 K=128 (3-term split-bf16), frag-major B loads
    v4f acc2[2][8];
    #pragma unroll
    for (int nt = 0; nt < 8; ++nt) {
        float bias = b2l[nt*16 + n16];
        acc2[0][nt] = (v4f){bias, bias, bias, bias};
        acc2[1][nt] = (v4f){bias, bias, bias, bias};
    }
    #pragma unroll
    for (int nt = 0; nt < 8; ++nt) {
        #pragma unroll
        for (int kc = 0; kc < 4; ++kc) {
            v8s bh = as_v8s(w2h [(nt*4 + kc)*64 + lane]);
            v8s bl = as_v8s(w2lo[(nt*4 + kc)*64 + lane]);
            acc2[0][nt] = mfma16(a2h[0][kc], bh, acc2[0][nt]);
            acc2[0][nt] = mfma16(a2l[0][kc], bh, acc2[0][nt]);
            acc2[0][nt] = mfma16(a2h[0][kc], bl, acc2[0][nt]);
            acc2[1][nt] = mfma16(a2h[1][kc], bh, acc2[1][nt]);
            acc2[1][nt] = mfma16(a2l[1][kc], bh, acc2[1][nt]);
            acc2[1][nt] = mfma16(a2h[1][kc], bl, acc2[1][nt]);
        }
    }

    // relu + RNE bf16 -> est
    #pragma unroll
    for (int mt = 0; mt < 2; ++mt)
        #pragma unroll
        for (int nt = 0; nt < 8; ++nt)
            #pragma unroll
            for (int rg = 0; rg < 4; ++rg) {
                float v = fmaxf(acc2[mt][nt][rg], 0.0f);
                int rr = mt*16 + q*4 + rg;
                esth[rr*132 + nt*16 + n16] = (uint16_t)f2bf1(v);
            }
    wave_lds_fence();

    // lse A-frags from est
    v8s af[2][4];
    #pragma unroll
    for (int mt = 0; mt < 2; ++mt)
        #pragma unroll
        for (int kc = 0; kc < 4; ++kc) {
            int ba = (mt*16 + n16)*66 + kc*16 + q*4;
            uint2 p0 = *(const uint2*)(estd + ba);
            uint2 p1 = *(const uint2*)(estd + ba + 2);
            af[mt][kc] = as_v8s(make_uint4(p0.x, p0.y, p1.x, p1.y));
        }
    wave_lds_fence();   // est fully read -> U overlay safe

    #pragma unroll
    for (int nt = 0; nt < 4; ++nt) {
        v4f acc0 = (v4f){0.f,0.f,0.f,0.f}, acc1 = (v4f){0.f,0.f,0.f,0.f};
        #pragma unroll
        for (int kc = 0; kc < 4; ++kc) {
            v8s bh = as_v8s(dh[(nt*4 + kc)*64 + lane]);
            v8s bl = as_v8s(dl[(nt*4 + kc)*64 + lane]);
            acc0 = mfma16(af[0][kc], bh, acc0);
            acc1 = mfma16(af[1][kc], bh, acc1);
            acc0 = mfma16(af[0][kc], bl, acc0);
            acc1 = mfma16(af[1][kc], bl, acc1);
        }
        #pragma unroll
        for (int rg = 0; rg < 4; ++rg) {
            Aw[(q*4 + rg)*65      + nt*16 + n16] = acc0[rg] + blv[0][rg];
            Aw[(16 + q*4 + rg)*65 + nt*16 + n16] = acc1[rg] + blv[1][rg];
        }
        float m = -3.0e38f, s = 0.0f;
        #pragma unroll
        for (int rg = 0; rg < 4; ++rg) {
            float u = acc0[rg] + blv[0][rg];
            if (vl[0][rg]) {
                float mn = fmaxf(m, u);
                s = s * __expf(m - mn) + __expf(u - mn);
                m = mn;
            }
        }
        #pragma unroll
        for (int rg = 0; rg < 4; ++rg) {
            float u = acc1[rg] + blv[1][rg];
            if (vl[1][rg]) {
                float mn = fmaxf(m, u);
                s = s * __expf(m - mn) + __expf(u - mn);
                m = mn;
            }
        }
        #pragma unroll
        for (int off = 16; off < 64; off <<= 1) {
            float m2 = __shfl_xor(m, off, 64);
            float s2 = __shfl_xor(s, off, 64);
            float mn = fmaxf(m, m2);
            s = s * __expf(m - mn) + s2 * __expf(m2 - mn);
            m = mn;
        }
        if (q == 0) {
            sred[(w*64 + nt*16 + n16)*2 + 0] = m;
            sred[(w*64 + nt*16 + n16)*2 + 1] = s;
        }
    }
    wave_lds_fence();

    // coalesced non-temporal U store
    #pragma unroll
    for (int c = 0; c < 8; ++c) {
        int row = c*4 + (lane >> 4);
        int col = (lane & 15) * 4;
        int glr = l0w + row;
        if (glr < 2000) {
            const float* src = Aw + row*65 + col;
            v4f v = {src[0], src[1], src[2], src[3]};
            __builtin_nontemporal_store(v, (v4f*)(U + ((size_t)(b*2000 + glr))*64 + col));
        }
    }

    __syncthreads();   // sred visible block-wide
    if (t < 64) {
        float m = sred[t*2 + 0], s = sred[t*2 + 1];
        #pragma unroll
        for (int ww = 1; ww < 4; ++ww) {
            float m2 = sred[(ww*64 + t)*2 + 0], s2 = sred[(ww*64 + t)*2 + 1];
            float mn = fmaxf(m, m2);
            s = s * __expf(m - mn) + s2 * __expf(m2 - mn);
            m = mn;
        }
        partials[((b*16 + chunk)*64 + t)*2 + 0] = m;
        partials[((b*16 + chunk)*64 + t)*2 + 1] = s;
    }
}

__global__ __launch_bounds__(64) void k_red(
    const float* __restrict__ partials, float* __restrict__ lse)
{
    int b = blockIdx.x, a = threadIdx.x;
    float m = -3.0e38f, s = 0.0f;
    for (int c = 0; c < 16; ++c) {
        float pm = partials[((b*16 + c)*64 + a)*2 + 0];
        float ps = partials[((b*16 + c)*64 + a)*2 + 1];
        float mn = fmaxf(m, pm);
        s = s * __expf(m - mn) + ps * __expf(pm - mn);
        m = mn;
    }
    lse[b*64 + a] = m + __logf(s);
}

// ---------------------------------------------------------------------------
// k_gather2 (r10-proven simple form): one fragment per thread.
// ---------------------------------------------------------------------------
__global__ __launch_bounds__(256) void k_gather2(
    const float* __restrict__ U, const float* __restrict__ lse,
    const int* __restrict__ labels, const int* __restrict__ cellix,
    const int* __restrict__ regionix, const int* __restrict__ binix,
    float* __restrict__ out)
{
    int f = blockIdx.x * 256 + threadIdx.x;
    if (f >= NF_) return;
    int b = regionix[f];
    int l = binix[f];
    int a = labels[cellix[f]];
    out[f] = U[((size_t)(b*2000 + l))*64 + a] - lse[b*64 + a] + LN_A;
}

extern "C" void kernel_launch(void* const* d_in, const int* in_sizes, int n_in,
                              void* d_out, int out_size, void* d_ws, size_t ws_size,
                              hipStream_t stream)
{
    const float* bincounts = (const float*)d_in[0];
    const float* conv1_w   = (const float*)d_in[1];
    const float* conv1_b   = (const float*)d_in[2];
    const float* conv2_w   = (const float*)d_in[3];
    const float* conv2_b   = (const float*)d_in[4];
    const float* lin1_w    = (const float*)d_in[5];
    const float* lin1_b    = (const float*)d_in[6];
    const float* lin2_w    = (const float*)d_in[7];
    const float* lin2_b    = (const float*)d_in[8];
    const float* baseline  = (const float*)d_in[9];
    const float* diff      = (const float*)d_in[10];
    const int*   regions   = (const int*)d_in[11];
    const int*   labels    = (const int*)d_in[12];
    const int*   cellix    = (const int*)d_in[13];
    const int*   regionix  = (const int*)d_in[14];
    const int*   binix     = (const int*)d_in[15];
    float* out = (float*)d_out;
    u32*   scr = (u32*)d_out;    // d_out doubles as scratch until k_gather2

    // ws: U fp32 [256*2000][64] = 131,072,000 B | lse f32 [256*64]
    const size_t u_words = (size_t)B_ * 2000 * 64;
    const size_t need = u_words*4 + (size_t)B_*64*4;
    if (ws_size < need) return;
    float* U   = (float*)d_ws;
    float* lse = U + u_words;

    const float* scf = (const float*)scr;
    float* partials = (float*)(scr + OFF_PART);

    w_prep  <<<dim3(307), dim3(256), 0, stream>>>(bincounts, conv1_w, conv1_b, conv2_w,
                                                  conv2_b, lin2_w, diff, scr);
    k_prep2 <<<dim3(518), dim3(256), 0, stream>>>(lin1_w, lin1_b, scr);
    k_front <<<dim3(B_*16), dim3(256), 0, stream>>>(bincounts, lin2_b,
                                                    scf + OFF_CW, scf + OFF_CB1,
                                                    scf + OFF_VC1,
                                                    (const uint4*)(scr + OFF_W2T_H),
                                                    (const uint4*)(scr + OFF_W2T_L),
                                                    (const uint4*)(scr + OFF_DIFF_H),
                                                    (const uint4*)(scr + OFF_DIFF_L),
                                                    baseline, regions, U, partials);
    k_red   <<<dim3(B_), dim3(64), 0, stream>>>(partials, lse);
    k_gather2<<<dim3((NF_+255)/256), dim3(256), 0, stream>>>(U, lse, labels, cellix,
                                                             regionix, binix, out);
}

// Round 14
// 228.632 us; speedup vs baseline: 1.5002x; 1.1104x over previous
//
#include <hip/hip_runtime.h>
#include <stdint.h>

typedef unsigned int u32;
typedef short v8s __attribute__((ext_vector_type(8)));
typedef float v4f __attribute__((ext_vector_type(4)));

#define B_ 256
#define NF_ 1000000
#define LN_A 5.545177444479562f

__device__ inline u32 f2bf1(float a) {
    u32 x = __float_as_uint(a);
    return (x + 0x7fffu + ((x >> 16) & 1u)) >> 16;
}
__device__ inline float bfval(float a) { return __uint_as_float(f2bf1(a) << 16); }
__device__ inline u32 packbf(float lo, float hi) { return f2bf1(lo) | (f2bf1(hi) << 16); }
__device__ inline v8s as_v8s(uint4 x) { union { uint4 a; v8s b; } u; u.a = x; return u.b; }
__device__ inline v4f mfma16(v8s a, v8s b, v4f c) {
    return __builtin_amdgcn_mfma_f32_16x16x32_bf16(a, b, c, 0, 0, 0);
}
__device__ inline void wave_lds_fence() {
    asm volatile("s_waitcnt lgkmcnt(0)" ::: "memory");
}

// truncation-split of 8 consecutive fp32 -> bf16 hi + lo frags (hi+lo exact)
__device__ inline void split8(const float* p, v8s& hi, v8s& lo) {
    u32 h[4], l[4];
    #pragma unroll
    for (int i = 0; i < 4; ++i) {
        float2 f = *(const float2*)(p + 2*i);
        u32 xa = __float_as_uint(f.x), xb = __float_as_uint(f.y);
        h[i] = __builtin_amdgcn_perm(xb, xa, 0x07060302u);
        float la = f.x - __uint_as_float(xa & 0xffff0000u);
        float lb = f.y - __uint_as_float(xb & 0xffff0000u);
        l[i] = __builtin_amdgcn_perm(__float_as_uint(lb), __float_as_uint(la), 0x07060302u);
    }
    hi = as_v8s(make_uint4(h[0], h[1], h[2], h[3]));
    lo = as_v8s(make_uint4(l[0], l[1], l[2], l[3]));
}

// d_out scratch layout (dword offsets)
#define OFF_W2T_H 8192
#define OFF_W2T_L 16384
#define OFF_DIFF_H 24576
#define OFF_DIFF_L 28672
#define OFF_WCOMP 32768
#define OFF_BCOMP 33344
#define OFF_VC    33408
#define OFF_CW    102400
#define OFF_CB1   103680
#define OFF_PART  131072      // [256][16][64][2]
#define OFF_VC1   655360      // [256][4][128]

// ---------------------------------------------------------------------------
// w_prep (verified r12): frag-major images + composite conv pieces
// ---------------------------------------------------------------------------
__global__ __launch_bounds__(256) void w_prep(
    const float* __restrict__ x,   const float* __restrict__ w1c,
    const float* __restrict__ b1c, const float* __restrict__ w2c,
    const float* __restrict__ b2c, const float* __restrict__ w2l,
    const float* __restrict__ diff, u32* __restrict__ scr)
{
    int idx = blockIdx.x * 256 + threadIdx.x;
    float* scf = (float*)scr;
    if (idx < 8192) {                        // w2 frag-major (nt 0..7)
        int inew = idx >> 2, comp = idx & 3;
        int nt = inew >> 8, kc = (inew >> 6) & 3, lane = inew & 63;
        int j = nt*16 + (lane & 15);
        int c = kc*16 + (lane >> 4)*4 + comp;
        float v0 = w2l[j*128 + 2*c], v1 = w2l[j*128 + 2*c + 1];
        scr[OFF_W2T_H + idx] = packbf(v0, v1);
        scr[OFF_W2T_L + idx] = packbf(v0 - bfval(v0), v1 - bfval(v1));
    } else if (idx < 12288) {                // diff frag-major (nt 0..3)
        int r = idx - 8192;
        int inew = r >> 2, comp = r & 3;
        int nt = inew >> 8, kc = (inew >> 6) & 3, lane = inew & 63;
        int a = nt*16 + (lane & 15);
        int c = kc*16 + (lane >> 4)*4 + comp;
        float v0 = diff[a*128 + 2*c], v1 = diff[a*128 + 2*c + 1];
        scr[OFF_DIFF_H + r] = packbf(v0, v1);
        scr[OFF_DIFF_L + r] = packbf(v0 - bfval(v0), v1 - bfval(v1));
    } else if (idx < 12864) {
        int r = idx - 12288, j = r >> 6, o = r & 63;
        float s = 0.0f;
        for (int k1 = 0; k1 < 5; ++k1) {
            int k2 = j - k1;
            if (k2 < 0 || k2 > 4) continue;
            for (int i = 0; i < 32; ++i)
                s += w1c[i*5 + k1] * w2c[o*160 + i*5 + k2];
        }
        scf[OFF_WCOMP + r] = s;
    } else if (idx < 12928) {
        int o = idx - 12864;
        float s = b2c[o];
        for (int i = 0; i < 32; ++i) {
            float b1 = b1c[i];
            for (int k2 = 0; k2 < 5; ++k2) s += w2c[o*160 + i*5 + k2] * b1;
        }
        scf[OFF_BCOMP + o] = s;
    } else if (idx >= 13056 && idx < 78592) {
        int r = idx - 13056;
        int b = r >> 8, q = (r >> 6) & 3, o = r & 63;
        float x0 = x[b*2000], x1 = x[b*2000 + 1];
        float xa = x[b*2000 + 1998], xb = x[b*2000 + 1999];
        float s = 0.0f;
        for (int i = 0; i < 32; ++i) {
            float b1 = b1c[i];
            if (q == 0) {
                float hvm2 = b1 + w1c[i*5 + 4]*x0;
                float hvm1 = b1 + w1c[i*5 + 3]*x0 + w1c[i*5 + 4]*x1;
                s += w2c[o*160 + i*5 + 0]*hvm2 + w2c[o*160 + i*5 + 1]*hvm1;
            } else if (q == 1) {
                float hvm1 = b1 + w1c[i*5 + 3]*x0 + w1c[i*5 + 4]*x1;
                s += w2c[o*160 + i*5 + 0]*hvm1;
            } else if (q == 2) {
                float hv0 = b1 + w1c[i*5 + 0]*xa + w1c[i*5 + 1]*xb;
                s += w2c[o*160 + i*5 + 4]*hv0;
            } else {
                float hv0 = b1 + w1c[i*5 + 0]*xa + w1c[i*5 + 1]*xb;
                float hv1 = b1 + w1c[i*5 + 0]*xb;
                s += w2c[o*160 + i*5 + 3]*hv0 + w2c[o*160 + i*5 + 4]*hv1;
            }
        }
        scf[OFF_VC + r] = s;
    }
}

// ---------------------------------------------------------------------------
// k_prep2 (verified r11-r12): w1l staged in LDS
// ---------------------------------------------------------------------------
__global__ __launch_bounds__(256) void k_prep2(
    const float* __restrict__ w1l, const float* __restrict__ b1l,
    u32* __restrict__ scr)
{
    __shared__ float w1s[8192];
    for (int i = threadIdx.x; i < 8192; i += 256) w1s[i] = w1l[i];
    __syncthreads();

    const float* scf = (const float*)scr;
    float* out = (float*)scr;
    int idx = blockIdx.x * 256 + threadIdx.x;
    if (idx < 1152) {
        int tap = idx >> 7, j = idx & 127;
        float s = 0.f;
        for (int o = 0; o < 64; ++o)
            s += w1s[j*64 + o] * scf[OFF_WCOMP + tap*64 + o];
        out[OFF_CW + idx] = s;
    } else if (idx < 1280) {
        int j = idx - 1152;
        float s = b1l[j];
        for (int o = 0; o < 64; ++o)
            s += w1s[j*64 + o] * scf[OFF_BCOMP + o];
        out[OFF_CB1 + j] = s;
    } else if (idx < 1280 + 131072) {
        int r = idx - 1280;
        int bq = r >> 7, j = r & 127;
        float s = 0.f;
        for (int o = 0; o < 64; ++o)
            s += w1s[j*64 + o] * scf[OFF_VC + bq*64 + o];
        out[OFF_VC1 + r] = s;
    }
}

// ---------------------------------------------------------------------------
// k_front v14: v12's PROVEN interleaved conv->split8 per mt sub-tile
// (the v13 hoist read stale/out-of-region rows — reverted), plus v13's
// nt-pair accumulators, two-pass masked softmax, and (256,4) occupancy.
// ---------------------------------------------------------------------------
__global__ __launch_bounds__(256, 4) void k_front(
    const float* __restrict__ x,   const float* __restrict__ b2l,
    const float* __restrict__ CW,  const float* __restrict__ cb1,
    const float* __restrict__ Vc1,
    const uint4* __restrict__ w2h, const uint4* __restrict__ w2lo,
    const uint4* __restrict__ dh,  const uint4* __restrict__ dl,
    const float* __restrict__ baseline, const int* __restrict__ regions,
    float* __restrict__ U, float* __restrict__ partials)
{
    __shared__ float smf[9136];
    const int b     = blockIdx.x >> 4;
    const int chunk = blockIdx.x & 15;
    const int t     = threadIdx.x;
    const int lane  = t & 63;
    const int w     = __builtin_amdgcn_readfirstlane(t >> 6);
    const int n16   = lane & 15;
    const int q     = lane >> 4;
    const int l0w   = (chunk << 7) + w*32;
    const int rrow  = regions[b];

    float* Aw   = smf + w*2156;
    float* xsw  = Aw + 2112;
    float* sred = smf + 8624;
    u32*  estd  = (u32*)Aw;
    uint16_t* esth = (uint16_t*)Aw;

    if (lane < 44) {
        int g = l0w - 4 + lane;
        xsw[lane] = (g >= 0 && g < 2000) ? x[b*2000 + g] : 0.0f;
    }
    wave_lds_fence();

    float cw0[9], cw1[9];
    #pragma unroll
    for (int d = 0; d < 9; ++d) {
        float2 c2 = *(const float2*)&CW[d*128 + 2*lane];
        cw0[d] = c2.x; cw1[d] = c2.y;
    }
    const float2 cb2 = *(const float2*)&cb1[2*lane];

    // interleaved conv -> frag extraction per 16-row sub-tile (v12-proven)
    v8s a2h[2][4], a2l[2][4];
    #pragma unroll
    for (int mt = 0; mt < 2; ++mt) {
        float win[9];
        #pragma unroll
        for (int d = 0; d < 9; ++d) win[d] = xsw[mt*16 + d];
        #pragma unroll
        for (int r = 0; r < 16; ++r) {
            int gl = l0w + mt*16 + r;
            float h0 = cb2.x, h1v = cb2.y;
            #pragma unroll
            for (int d = 0; d < 9; ++d) { h0 += win[d]*cw0[d]; h1v += win[d]*cw1[d]; }
            if (gl <= 1) {
                float2 v = *(const float2*)&Vc1[(b*4 + gl)*128 + 2*lane];
                h0 -= v.x; h1v -= v.y;
            } else if (gl >= 1998 && gl < 2000) {
                float2 v = *(const float2*)&Vc1[(b*4 + gl - 1996)*128 + 2*lane];
                h0 -= v.x; h1v -= v.y;
            }
            *(float2*)&Aw[r*130 + 2*lane] = make_float2(fmaxf(h0, 0.f), fmaxf(h1v, 0.f));
            #pragma unroll
            for (int d = 0; d < 8; ++d) win[d] = win[d+1];
            win[8] = xsw[mt*16 + r + 9];
        }
        wave_lds_fence();
        #pragma unroll
        for (int kc = 0; kc < 4; ++kc)
            split8(&Aw[n16*130 + kc*32 + q*8], a2h[mt][kc], a2l[mt][kc]);
        wave_lds_fence();
    }

    // lin2 + relu, nt in PAIRS with immediate epilogue (16 AGPR live)
    #pragma unroll
    for (int np = 0; np < 4; ++np) {
        v4f acc[2][2];
        #pragma unroll
        for (int i = 0; i < 2; ++i) {
            float bias = b2l[(np*2 + i)*16 + n16];
            acc[0][i] = (v4f){bias, bias, bias, bias};
            acc[1][i] = (v4f){bias, bias, bias, bias};
        }
        #pragma unroll
        for (int i = 0; i < 2; ++i) {
            int nt = np*2 + i;
            #pragma unroll
            for (int kc = 0; kc < 4; ++kc) {
                v8s bh = as_v8s(w2h [(nt*4 + kc)*64 + lane]);
                v8s bl = as_v8s(w2lo[(nt*4 + kc)*64 + lane]);
                acc[0][i] = mfma16(a2h[0][kc], bh, acc[0][i]);
                acc[0][i] = mfma16(a2l[0][kc], bh, acc[0][i]);
                acc[0][i] = mfma16(a2h[0][kc], bl, acc[0][i]);
                acc[1][i] = mfma16(a2h[1][kc], bh, acc[1][i]);
                acc[1][i] = mfma16(a2l[1][kc], bh, acc[1][i]);
                acc[1][i] = mfma16(a2h[1][kc], bl, acc[1][i]);
            }
        }
        #pragma unroll
        for (int i = 0; i < 2; ++i) {
            int nt = np*2 + i;
            #pragma unroll
            for (int mt = 0; mt < 2; ++mt)
                #pragma unroll
                for (int rg = 0; rg < 4; ++rg) {
                    float v = fmaxf(acc[mt][i][rg], 0.0f);
                    int rr = mt*16 + q*4 + rg;
                    esth[rr*132 + nt*16 + n16] = (uint16_t)f2bf1(v);
                }
        }
    }
    wave_lds_fence();

    // lse A-frags from est
    v8s af[2][4];
    #pragma unroll
    for (int mt = 0; mt < 2; ++mt)
        #pragma unroll
        for (int kc = 0; kc < 4; ++kc) {
            int ba = (mt*16 + n16)*66 + kc*16 + q*4;
            uint2 p0 = *(const uint2*)(estd + ba);
            uint2 p1 = *(const uint2*)(estd + ba + 2);
            af[mt][kc] = as_v8s(make_uint4(p0.x, p0.y, p1.x, p1.y));
        }
    wave_lds_fence();   // est fully read -> U overlay safe

    float blv[2][4];
    bool  vl[2][4];
    #pragma unroll
    for (int mt = 0; mt < 2; ++mt)
        #pragma unroll
        for (int rg = 0; rg < 4; ++rg) {
            int rl = l0w + mt*16 + q*4 + rg;
            vl[mt][rg] = rl < 2000;
            blv[mt][rg] = baseline[rrow*2000 + (rl < 2000 ? rl : 1999)];
        }

    #pragma unroll
    for (int nt = 0; nt < 4; ++nt) {
        v4f acc0 = (v4f){0.f,0.f,0.f,0.f}, acc1 = (v4f){0.f,0.f,0.f,0.f};
        #pragma unroll
        for (int kc = 0; kc < 4; ++kc) {
            v8s bh = as_v8s(dh[(nt*4 + kc)*64 + lane]);
            v8s bl = as_v8s(dl[(nt*4 + kc)*64 + lane]);
            acc0 = mfma16(af[0][kc], bh, acc0);
            acc1 = mfma16(af[1][kc], bh, acc1);
            acc0 = mfma16(af[0][kc], bl, acc0);
            acc1 = mfma16(af[1][kc], bl, acc1);
        }
        // stash U+base (unmasked) for the global store
        float uu[8];
        #pragma unroll
        for (int rg = 0; rg < 4; ++rg) {
            float u0 = acc0[rg] + blv[0][rg];
            float u1 = acc1[rg] + blv[1][rg];
            Aw[(q*4 + rg)*65      + nt*16 + n16] = u0;
            Aw[(16 + q*4 + rg)*65 + nt*16 + n16] = u1;
            uu[rg]     = vl[0][rg] ? u0 : -3.0e38f;
            uu[4 + rg] = vl[1][rg] ? u1 : -3.0e38f;
        }
        // two-pass: masked max -> cross-q max -> one exp/elem -> add reduce
        float M = uu[0];
        #pragma unroll
        for (int j = 1; j < 8; ++j) M = fmaxf(M, uu[j]);
        M = fmaxf(M, __shfl_xor(M, 16, 64));
        M = fmaxf(M, __shfl_xor(M, 32, 64));
        float s = 0.0f;
        #pragma unroll
        for (int j = 0; j < 8; ++j) s += __expf(uu[j] - M);
        s += __shfl_xor(s, 16, 64);
        s += __shfl_xor(s, 32, 64);
        if (q == 0) {
            sred[(w*64 + nt*16 + n16)*2 + 0] = M;
            sred[(w*64 + nt*16 + n16)*2 + 1] = s;
        }
    }
    wave_lds_fence();

    // coalesced non-temporal U store
    #pragma unroll
    for (int c = 0; c < 8; ++c) {
        int row = c*4 + (lane >> 4);
        int col = (lane & 15) * 4;
        int glr = l0w + row;
        if (glr < 2000) {
            const float* src = Aw + row*65 + col;
            v4f v = {src[0], src[1], src[2], src[3]};
            __builtin_nontemporal_store(v, (v4f*)(U + ((size_t)(b*2000 + glr))*64 + col));
        }
    }

    __syncthreads();   // sred visible block-wide
    if (t < 64) {
        float m = sred[t*2 + 0], s = sred[t*2 + 1];
        #pragma unroll
        for (int ww = 1; ww < 4; ++ww) {
            float m2 = sred[(ww*64 + t)*2 + 0], s2 = sred[(ww*64 + t)*2 + 1];
            float mn = fmaxf(m, m2);
            s = s * __expf(m - mn) + s2 * __expf(m2 - mn);
            m = mn;
        }
        partials[((b*16 + chunk)*64 + t)*2 + 0] = m;
        partials[((b*16 + chunk)*64 + t)*2 + 1] = s;
    }
}

__global__ __launch_bounds__(64) void k_red(
    const float* __restrict__ partials, float* __restrict__ lse)
{
    int b = blockIdx.x, a = threadIdx.x;
    float m = -3.0e38f, s = 0.0f;
    for (int c = 0; c < 16; ++c) {
        float pm = partials[((b*16 + c)*64 + a)*2 + 0];
        float ps = partials[((b*16 + c)*64 + a)*2 + 1];
        float mn = fmaxf(m, pm);
        s = s * __expf(m - mn) + ps * __expf(pm - mn);
        m = mn;
    }
    lse[b*64 + a] = m + __logf(s);
}

// ---------------------------------------------------------------------------
// k_gather2 (r10/r12-proven): one fragment per thread.
// ---------------------------------------------------------------------------
__global__ __launch_bounds__(256) void k_gather2(
    const float* __restrict__ U, const float* __restrict__ lse,
    const int* __restrict__ labels, const int* __restrict__ cellix,
    const int* __restrict__ regionix, const int* __restrict__ binix,
    float* __restrict__ out)
{
    int f = blockIdx.x * 256 + threadIdx.x;
    if (f >= NF_) return;
    int b = regionix[f];
    int l = binix[f];
    int a = labels[cellix[f]];
    out[f] = U[((size_t)(b*2000 + l))*64 + a] - lse[b*64 + a] + LN_A;
}

extern "C" void kernel_launch(void* const* d_in, const int* in_sizes, int n_in,
                              void* d_out, int out_size, void* d_ws, size_t ws_size,
                              hipStream_t stream)
{
    const float* bincounts = (const float*)d_in[0];
    const float* conv1_w   = (const float*)d_in[1];
    const float* conv1_b   = (const float*)d_in[2];
    const float* conv2_w   = (const float*)d_in[3];
    const float* conv2_b   = (const float*)d_in[4];
    const float* lin1_w    = (const float*)d_in[5];
    const float* lin1_b    = (const float*)d_in[6];
    const float* lin2_w    = (const float*)d_in[7];
    const float* lin2_b    = (const float*)d_in[8];
    const float* baseline  = (const float*)d_in[9];
    const float* diff      = (const float*)d_in[10];
    const int*   regions   = (const int*)d_in[11];
    const int*   labels    = (const int*)d_in[12];
    const int*   cellix    = (const int*)d_in[13];
    const int*   regionix  = (const int*)d_in[14];
    const int*   binix     = (const int*)d_in[15];
    float* out = (float*)d_out;
    u32*   scr = (u32*)d_out;    // d_out doubles as scratch until k_gather2

    // ws: U fp32 [256*2000][64] = 131,072,000 B | lse f32 [256*64]
    const size_t u_words = (size_t)B_ * 2000 * 64;
    const size_t need = u_words*4 + (size_t)B_*64*4;
    if (ws_size < need) return;
    float* U   = (float*)d_ws;
    float* lse = U + u_words;

    const float* scf = (const float*)scr;
    float* partials = (float*)(scr + OFF_PART);

    w_prep  <<<dim3(307), dim3(256), 0, stream>>>(bincounts, conv1_w, conv1_b, conv2_w,
                                                  conv2_b, lin2_w, diff, scr);
    k_prep2 <<<dim3(518), dim3(256), 0, stream>>>(lin1_w, lin1_b, scr);
    k_front <<<dim3(B_*16), dim3(256), 0, stream>>>(bincounts, lin2_b,
                                                    scf + OFF_CW, scf + OFF_CB1,
                                                    scf + OFF_VC1,
                                                    (const uint4*)(scr + OFF_W2T_H),
                                                    (const uint4*)(scr + OFF_W2T_L),
                                                    (const uint4*)(scr + OFF_DIFF_H),
                                                    (const uint4*)(scr + OFF_DIFF_L),
                                                    baseline, regions, U, partials);
    k_red   <<<dim3(B_), dim3(64), 0, stream>>>(partials, lse);
    k_gather2<<<dim3((NF_+255)/256), dim3(256), 0, stream>>>(U, lse, labels, cellix,
                                                             regionix, binix, out);
}